// Round 6
// baseline (159.107 us; speedup 1.0000x reference)
//
#include <hip/hip_runtime.h>

typedef __attribute__((ext_vector_type(8))) short bf16x8;
typedef __attribute__((ext_vector_type(4))) short bf16x4;
typedef __attribute__((ext_vector_type(4))) float f32x4;
typedef unsigned short u16;
typedef unsigned int u32;

#define MFMA16(a, b, c) __builtin_amdgcn_mfma_f32_16x16x32_bf16((a), (b), (c), 0, 0, 0)

__device__ __forceinline__ u16 f2b(float f) {
    u32 u = __float_as_uint(f);
    u32 r = u + 0x7fffu + ((u >> 16) & 1u);
    return (u16)(r >> 16);
}
__device__ __forceinline__ float b2f(u16 u) { return __uint_as_float(((u32)u) << 16); }
__device__ __forceinline__ u32 packbf(float lo, float hi) {
    return (u32)f2b(lo) | ((u32)f2b(hi) << 16);
}

// ---------------- converts ----------------
__global__ void k_f32_to_bf16(const float* __restrict__ in, u16* __restrict__ out, int n) {
    int i = (blockIdx.x * blockDim.x + threadIdx.x) * 4;
    if (i + 3 < n) {
        float4 v = *(const float4*)(in + i);
        out[i] = f2b(v.x); out[i + 1] = f2b(v.y); out[i + 2] = f2b(v.z); out[i + 3] = f2b(v.w);
    } else {
        for (int j = i; j < n; ++j) out[j] = f2b(in[j]);
    }
}

__global__ void k_make_wqkv_t(const float* __restrict__ Wq, const float* __restrict__ Wkv,
                              u16* __restrict__ wt) {
    int tid = blockIdx.x * blockDim.x + threadIdx.x;  // 786432 total
    int k = tid & 511, n = tid >> 9;
    float v = (n < 512) ? Wq[k * 512 + n] : Wkv[k * 1024 + (n - 512)];
    wt[n * 512 + k] = f2b(v);
}

__global__ void k_make_wo_t(const float* __restrict__ Wo, u16* __restrict__ wt) {
    int tid = blockIdx.x * blockDim.x + threadIdx.x;  // 262144 total
    int k = tid & 511, n = tid >> 9;
    wt[n * 512 + k] = f2b(Wo[k * 512 + n]);
}

// ---------------- GEMM 1: qkv = xb @ Wqkv  (M=8192, N=1536, K=512) ----------------
__global__ __launch_bounds__(256) void k_gemm_qkv(const u16* __restrict__ A, const u16* __restrict__ Bt,
                                                  u16* __restrict__ Q, u16* __restrict__ K,
                                                  u16* __restrict__ V) {
    __shared__ u16 As[128][40];
    __shared__ u16 Bs[128][40];
    const int t = threadIdx.x, l = t & 63, w = t >> 6;
    const int wr = w >> 1, wc = w & 1, l15 = l & 15, lg = l >> 4;
    const int m0 = blockIdx.x * 128, n0 = blockIdx.y * 128;
    f32x4 acc[4][4];
#pragma unroll
    for (int i = 0; i < 4; ++i)
#pragma unroll
        for (int j = 0; j < 4; ++j) acc[i][j] = (f32x4){0.f, 0.f, 0.f, 0.f};
    const int sr = t >> 1, sko = (t & 1) * 16;
    for (int k0 = 0; k0 < 512; k0 += 32) {
        __syncthreads();
        {
            const bf16x8* pa = (const bf16x8*)(A + (size_t)(m0 + sr) * 512 + k0 + sko);
            *(bf16x8*)&As[sr][sko] = pa[0];
            *(bf16x8*)&As[sr][sko + 8] = pa[1];
            const bf16x8* pb = (const bf16x8*)(Bt + (size_t)(n0 + sr) * 512 + k0 + sko);
            *(bf16x8*)&Bs[sr][sko] = pb[0];
            *(bf16x8*)&Bs[sr][sko + 8] = pb[1];
        }
        __syncthreads();
        bf16x8 af[4], bfr[4];
#pragma unroll
        for (int rt = 0; rt < 4; ++rt) af[rt] = *(const bf16x8*)&As[wr * 64 + rt * 16 + l15][lg * 8];
#pragma unroll
        for (int ct = 0; ct < 4; ++ct) bfr[ct] = *(const bf16x8*)&Bs[wc * 64 + ct * 16 + l15][lg * 8];
#pragma unroll
        for (int rt = 0; rt < 4; ++rt)
#pragma unroll
            for (int ct = 0; ct < 4; ++ct) acc[rt][ct] = MFMA16(af[rt], bfr[ct], acc[rt][ct]);
    }
#pragma unroll
    for (int rt = 0; rt < 4; ++rt)
#pragma unroll
        for (int ct = 0; ct < 4; ++ct) {
            int n = n0 + wc * 64 + ct * 16 + l15;
            int sec = n >> 9, nn = n & 511, h = nn >> 6, d = nn & 63;
            u16* dst = (sec == 0) ? Q : ((sec == 1) ? K : V);
#pragma unroll
            for (int r = 0; r < 4; ++r) {
                int m = m0 + wr * 64 + rt * 16 + lg * 4 + r;
                int b = m >> 10, pos = m & 1023, bh = b * 8 + h;
                dst[(size_t)bh * 65536 + (size_t)pos * 64 + d] = f2b(acc[rt][ct][r]);
            }
        }
}

// ---------------- V transpose: Vt[bh][d][pos] = V[bh][pos][d] ----------------
__global__ __launch_bounds__(256) void k_transpose_v(const u16* __restrict__ V, u16* __restrict__ Vt) {
    __shared__ u16 tile[64][72];
    const int bh = blockIdx.x >> 4, pt = blockIdx.x & 15;
    const int p0 = pt * 64;
    const int t = threadIdx.x, r = t >> 2, c0 = (t & 3) * 16;
    const bf16x8* src = (const bf16x8*)(V + (size_t)bh * 65536 + (size_t)(p0 + r) * 64 + c0);
    *(bf16x8*)&tile[r][c0] = src[0];
    *(bf16x8*)&tile[r][c0 + 8] = src[1];
    __syncthreads();
    union { u16 u[8]; bf16x8 v; } o0, o1;
#pragma unroll
    for (int ii = 0; ii < 8; ++ii) {
        o0.u[ii] = tile[c0 + ii][r];
        o1.u[ii] = tile[c0 + 8 + ii][r];
    }
    bf16x8* dst = (bf16x8*)(Vt + (size_t)bh * 65536 + (size_t)r * 1024 + p0 + c0);
    dst[0] = o0.v;
    dst[1] = o1.v;
}

// ---------------- flash attention, swapped-operand (S^T) layout ----------------
// Swapped math (mfma(K,Q)/mfma(rel,Q)/mfma(V,P)) kept from R5; ALL risky
// scheduling reverted to proven forms: R2 single-buffer staging skeleton
// (2 barriers) + explicit barrier fencing the sdw band (3 barriers/iter),
// __expf softmax, pure-C++ f2b packing (no inline asm), (512,2) bounds.
__global__ __launch_bounds__(512, 2) void k_attn(const u16* __restrict__ Q, const u16* __restrict__ K,
                                                 const u16* __restrict__ Vt, const u16* __restrict__ relb,
                                                 u16* __restrict__ Ob) {
    __shared__ u16 Ks[64][72];       // [j within tile][d]
    __shared__ u16 Vs[64][72];       // [d][j within tile]
    __shared__ u32 sdw[8][16][42];   // per-wave rel band: 80 bf16 packed in 40 u32
    const int t = threadIdx.x, l = t & 63, w = t >> 6;
    const int l15 = l & 15, lg = l >> 4;
    const int g = (blockIdx.x & 7) * 64 + (blockIdx.x >> 3);   // XCD swizzle
    const int bh = g >> 3;
    const int iw = (g & 7) * 128 + w * 16;
    const size_t hb = (size_t)bh * 65536;
    const int srow = t >> 3, scol = (t & 7) * 8;

    bf16x8 qf[2];
#pragma unroll
    for (int kf = 0; kf < 2; ++kf)
        qf[kf] = *(const bf16x8*)(Q + hb + (size_t)(iw + l15) * 64 + kf * 32 + lg * 8);

    f32x4 acc_o[4];
#pragma unroll
    for (int i = 0; i < 4; ++i) acc_o[i] = (f32x4){0.f, 0.f, 0.f, 0.f};
    float m_r = -1e30f, l_r = 0.f;

    // prologue: stage tile 0, prefetch tile 1 into regs (R2-proven skeleton)
    bf16x8 kreg = *(const bf16x8*)(K + hb + (size_t)srow * 64 + scol);
    bf16x8 vreg = *(const bf16x8*)(Vt + hb + (size_t)srow * 1024 + scol);
    *(bf16x8*)&Ks[srow][scol] = kreg;
    *(bf16x8*)&Vs[srow][scol] = vreg;
    kreg = *(const bf16x8*)(K + hb + (size_t)(64 + srow) * 64 + scol);
    vreg = *(const bf16x8*)(Vt + hb + (size_t)srow * 1024 + 64 + scol);
    __syncthreads();

    for (int j0 = 0; j0 < 1024; j0 += 64) {
        // S^T = mfma(K, Q): acc_s[c][r] = S[q = iw+l15][j = j0 + c*16 + lg*4 + r]
        f32x4 acc_s[4];
#pragma unroll
        for (int c = 0; c < 4; ++c) {
            acc_s[c] = (f32x4){0.f, 0.f, 0.f, 0.f};
#pragma unroll
            for (int kf = 0; kf < 2; ++kf) {
                bf16x8 kb = *(const bf16x8*)&Ks[c * 16 + l15][kf * 32 + lg * 8];
                acc_s[c] = MFMA16(kb, qf[kf], acc_s[c]);
            }
        }
        // band^T = mfma(rel, Q): lane(l15,lg) reg r holds band[t = pt*16+lg*4+r][q-row l15]
        const int bd = iw - j0 - 63;
#pragma unroll
        for (int pt = 0; pt < 5; ++pt) {
            int dd = bd + pt * 16 + l15;
            dd = dd < -512 ? -512 : (dd > 512 ? 512 : dd);
            const u16* rrow = relb + (size_t)(dd + 512) * 64;
            f32x4 a = (f32x4){0.f, 0.f, 0.f, 0.f};
#pragma unroll
            for (int kf = 0; kf < 2; ++kf) {
                bf16x8 rb = *(const bf16x8*)(rrow + kf * 32 + lg * 8);
                a = MFMA16(rb, qf[kf], a);
            }
            int wc32 = pt * 8 + lg * 2;
            sdw[w][l15][wc32] = packbf(a[0], a[1]);
            sdw[w][l15][wc32 + 1] = packbf(a[2], a[3]);
        }
        __syncthreads();   // fence band writes (and end of Ks reads)
        // gather band + scale: row is lane-local (l15)
        float sv[4][4];
#pragma unroll
        for (int c = 0; c < 4; ++c)
#pragma unroll
            for (int r = 0; r < 4; ++r) {
                int tt = l15 + 63 - c * 16 - lg * 4 - r;
                u32 wv = sdw[w][l15][tt >> 1];
                float band = b2f((u16)(wv >> ((tt & 1) * 16)));
                sv[c][r] = (acc_s[c][r] + band) * 0.125f;
            }
        // online softmax: in-lane tree + 2 shuffles across the 4 lane-groups
        float mt = sv[0][0];
#pragma unroll
        for (int c = 0; c < 4; ++c)
#pragma unroll
            for (int r = 0; r < 4; ++r) mt = fmaxf(mt, sv[c][r]);
        mt = fmaxf(mt, __shfl_xor(mt, 16, 64));
        mt = fmaxf(mt, __shfl_xor(mt, 32, 64));
        float mnew = fmaxf(m_r, mt);
        float alpha = __expf(m_r - mnew);
        m_r = mnew;
        float p[4][4];
        float rs = 0.f;
#pragma unroll
        for (int c = 0; c < 4; ++c)
#pragma unroll
            for (int r = 0; r < 4; ++r) {
                p[c][r] = __expf(sv[c][r] - mnew);
                rs += p[c][r];
            }
        rs += __shfl_xor(rs, 16, 64);
        rs += __shfl_xor(rs, 32, 64);
        l_r = l_r * alpha + rs;
#pragma unroll
        for (int dt = 0; dt < 4; ++dt)
#pragma unroll
            for (int r = 0; r < 4; ++r) acc_o[dt][r] *= alpha;
        // P B-frags via sigma(kf,lg,e) = kf*32 + (e>>2)*16 + lg*4 + (e&3): lane-local
        union { u32 wd[4]; bf16x8 v; } pb[2];
#pragma unroll
        for (int kf = 0; kf < 2; ++kf)
#pragma unroll
            for (int h = 0; h < 4; ++h) {
                int c = kf * 2 + (h >> 1), r0 = (h & 1) * 2;
                pb[kf].wd[h] = packbf(p[c][r0], p[c][r0 + 1]);
            }
        // O^T += mfma(V, P): acc_o[dt][r] = O[q = iw+l15][dcol = dt*16 + lg*4 + r]
#pragma unroll
        for (int dt = 0; dt < 4; ++dt)
#pragma unroll
            for (int kf = 0; kf < 2; ++kf) {
                union { bf16x4 h[2]; bf16x8 v; } vb;
                vb.h[0] = *(const bf16x4*)&Vs[dt * 16 + l15][kf * 32 + lg * 4];
                vb.h[1] = *(const bf16x4*)&Vs[dt * 16 + l15][kf * 32 + 16 + lg * 4];
                acc_o[dt] = MFMA16(vb.v, pb[kf].v, acc_o[dt]);
            }
        __syncthreads();   // all waves done reading Ks/Vs
        if (j0 + 64 < 1024) {
            *(bf16x8*)&Ks[srow][scol] = kreg;   // implicit vmcnt wait on prefetch
            *(bf16x8*)&Vs[srow][scol] = vreg;
            int jp = j0 / 64 + 2;
            if (jp > 15) jp = 15;
            kreg = *(const bf16x8*)(K + hb + (size_t)(jp * 64 + srow) * 64 + scol);
            vreg = *(const bf16x8*)(Vt + hb + (size_t)srow * 1024 + jp * 64 + scol);
            __syncthreads();   // staged tile visible
        }
    }
    const int b = bh >> 3, h = bh & 7;
    const float rinv = 1.0f / l_r;
    const size_t rowbase = (size_t)(b * 1024 + iw + l15) * 512 + h * 64;
#pragma unroll
    for (int dt = 0; dt < 4; ++dt)
#pragma unroll
        for (int r = 0; r < 4; ++r)
            Ob[rowbase + dt * 16 + lg * 4 + r] = f2b(acc_o[dt][r] * rinv);
}

// ---------------- GEMM 2: out = Ob @ Wo + bo  (M=8192, N=512, K=512, fp32 out) ----------------
__global__ __launch_bounds__(256) void k_gemm_out(const u16* __restrict__ A, const u16* __restrict__ Bt,
                                                  const float* __restrict__ bias, float* __restrict__ out) {
    __shared__ u16 As[128][40];
    __shared__ u16 Bs[128][40];
    const int t = threadIdx.x, l = t & 63, w = t >> 6;
    const int wr = w >> 1, wc = w & 1, l15 = l & 15, lg = l >> 4;
    const int m0 = blockIdx.x * 128, n0 = blockIdx.y * 128;
    f32x4 acc[4][4];
#pragma unroll
    for (int i = 0; i < 4; ++i)
#pragma unroll
        for (int j = 0; j < 4; ++j) acc[i][j] = (f32x4){0.f, 0.f, 0.f, 0.f};
    const int sr = t >> 1, sko = (t & 1) * 16;
    for (int k0 = 0; k0 < 512; k0 += 32) {
        __syncthreads();
        {
            const bf16x8* pa = (const bf16x8*)(A + (size_t)(m0 + sr) * 512 + k0 + sko);
            *(bf16x8*)&As[sr][sko] = pa[0];
            *(bf16x8*)&As[sr][sko + 8] = pa[1];
            const bf16x8* pb = (const bf16x8*)(Bt + (size_t)(n0 + sr) * 512 + k0 + sko);
            *(bf16x8*)&Bs[sr][sko] = pb[0];
            *(bf16x8*)&Bs[sr][sko + 8] = pb[1];
        }
        __syncthreads();
        bf16x8 af[4], bfr[4];
#pragma unroll
        for (int rt = 0; rt < 4; ++rt) af[rt] = *(const bf16x8*)&As[wr * 64 + rt * 16 + l15][lg * 8];
#pragma unroll
        for (int ct = 0; ct < 4; ++ct) bfr[ct] = *(const bf16x8*)&Bs[wc * 64 + ct * 16 + l15][lg * 8];
#pragma unroll
        for (int rt = 0; rt < 4; ++rt)
#pragma unroll
            for (int ct = 0; ct < 4; ++ct) acc[rt][ct] = MFMA16(af[rt], bfr[ct], acc[rt][ct]);
    }
#pragma unroll
    for (int rt = 0; rt < 4; ++rt)
#pragma unroll
        for (int ct = 0; ct < 4; ++ct) {
            int n = n0 + wc * 64 + ct * 16 + l15;
            float bv = bias[n];
#pragma unroll
            for (int r = 0; r < 4; ++r) {
                int m = m0 + wr * 64 + rt * 16 + lg * 4 + r;
                out[(size_t)m * 512 + n] = acc[rt][ct][r] + bv;
            }
        }
}

extern "C" void kernel_launch(void* const* d_in, const int* in_sizes, int n_in,
                              void* d_out, int out_size, void* d_ws, size_t ws_size,
                              hipStream_t stream) {
    const float* x    = (const float*)d_in[0];
    const float* Wq   = (const float*)d_in[1];
    const float* Wkv  = (const float*)d_in[2];
    const float* rel  = (const float*)d_in[3];
    const float* Wo   = (const float*)d_in[4];
    const float* bo   = (const float*)d_in[5];
    float* out = (float*)d_out;
    char* ws = (char*)d_ws;

    u16* xb   = (u16*)(ws + 0);          //  8,388,608 B
    u16* wqkv = (u16*)(ws + 8388608);    //  1,572,864 B
    u16* wot  = (u16*)(ws + 9961472);    //    524,288 B
    u16* relb = (u16*)(ws + 10485760);   //    131,200 B
    u16* Q    = (u16*)(ws + 10616960);   //  8,388,608 B
    u16* K    = (u16*)(ws + 19005568);   //  8,388,608 B
    u16* V    = (u16*)(ws + 27394176);   //  8,388,608 B
    u16* Vt   = (u16*)(ws + 35782784);   //  8,388,608 B
    u16* Ob   = (u16*)(ws + 44171392);   //  8,388,608 B

    k_f32_to_bf16<<<4096, 256, 0, stream>>>(x, xb, 4194304);
    k_f32_to_bf16<<<65, 256, 0, stream>>>(rel, relb, 65600);
    k_make_wqkv_t<<<3072, 256, 0, stream>>>(Wq, Wkv, wqkv);
    k_make_wo_t<<<1024, 256, 0, stream>>>(Wo, wot);
    k_gemm_qkv<<<dim3(64, 12), 256, 0, stream>>>(xb, wqkv, Q, K, V);
    k_transpose_v<<<1024, 256, 0, stream>>>(V, Vt);
    k_attn<<<512, 512, 0, stream>>>(Q, K, Vt, relb, Ob);
    k_gemm_out<<<dim3(64, 4), 256, 0, stream>>>(Ob, wot, bo, out);
}

// Round 8
// 150.487 us; speedup vs baseline: 1.0573x; 1.0573x over previous
//
#include <hip/hip_runtime.h>

typedef __attribute__((ext_vector_type(8))) short bf16x8;
typedef __attribute__((ext_vector_type(4))) short bf16x4;
typedef __attribute__((ext_vector_type(4))) float f32x4;
typedef unsigned short u16;
typedef unsigned int u32;

#define MFMA16(a, b, c) __builtin_amdgcn_mfma_f32_16x16x32_bf16((a), (b), (c), 0, 0, 0)

__device__ __forceinline__ u16 f2b(float f) {
    u32 u = __float_as_uint(f);
    u32 r = u + 0x7fffu + ((u >> 16) & 1u);
    return (u16)(r >> 16);
}
__device__ __forceinline__ float b2f(u16 u) { return __uint_as_float(((u32)u) << 16); }
__device__ __forceinline__ u32 packbf(float lo, float hi) {
    return (u32)f2b(lo) | ((u32)f2b(hi) << 16);
}

// ---------------- converts ----------------
__global__ void k_f32_to_bf16(const float* __restrict__ in, u16* __restrict__ out, int n) {
    int i = (blockIdx.x * blockDim.x + threadIdx.x) * 4;
    if (i + 3 < n) {
        float4 v = *(const float4*)(in + i);
        out[i] = f2b(v.x); out[i + 1] = f2b(v.y); out[i + 2] = f2b(v.z); out[i + 3] = f2b(v.w);
    } else {
        for (int j = i; j < n; ++j) out[j] = f2b(in[j]);
    }
}

__global__ void k_make_wqkv_t(const float* __restrict__ Wq, const float* __restrict__ Wkv,
                              u16* __restrict__ wt) {
    int tid = blockIdx.x * blockDim.x + threadIdx.x;  // 786432 total
    int k = tid & 511, n = tid >> 9;
    float v = (n < 512) ? Wq[k * 512 + n] : Wkv[k * 1024 + (n - 512)];
    wt[n * 512 + k] = f2b(v);
}

__global__ void k_make_wo_t(const float* __restrict__ Wo, u16* __restrict__ wt) {
    int tid = blockIdx.x * blockDim.x + threadIdx.x;  // 262144 total
    int k = tid & 511, n = tid >> 9;
    wt[n * 512 + k] = f2b(Wo[k * 512 + n]);
}

// ---------------- GEMM 1: qkv = xb @ Wqkv  (M=8192, N=1536, K=512) ----------------
__global__ __launch_bounds__(256) void k_gemm_qkv(const u16* __restrict__ A, const u16* __restrict__ Bt,
                                                  u16* __restrict__ Q, u16* __restrict__ K,
                                                  u16* __restrict__ V) {
    __shared__ u16 As[128][40];
    __shared__ u16 Bs[128][40];
    const int t = threadIdx.x, l = t & 63, w = t >> 6;
    const int wr = w >> 1, wc = w & 1, l15 = l & 15, lg = l >> 4;
    const int m0 = blockIdx.x * 128, n0 = blockIdx.y * 128;
    f32x4 acc[4][4];
#pragma unroll
    for (int i = 0; i < 4; ++i)
#pragma unroll
        for (int j = 0; j < 4; ++j) acc[i][j] = (f32x4){0.f, 0.f, 0.f, 0.f};
    const int sr = t >> 1, sko = (t & 1) * 16;
    for (int k0 = 0; k0 < 512; k0 += 32) {
        __syncthreads();
        {
            const bf16x8* pa = (const bf16x8*)(A + (size_t)(m0 + sr) * 512 + k0 + sko);
            *(bf16x8*)&As[sr][sko] = pa[0];
            *(bf16x8*)&As[sr][sko + 8] = pa[1];
            const bf16x8* pb = (const bf16x8*)(Bt + (size_t)(n0 + sr) * 512 + k0 + sko);
            *(bf16x8*)&Bs[sr][sko] = pb[0];
            *(bf16x8*)&Bs[sr][sko + 8] = pb[1];
        }
        __syncthreads();
        bf16x8 af[4], bfr[4];
#pragma unroll
        for (int rt = 0; rt < 4; ++rt) af[rt] = *(const bf16x8*)&As[wr * 64 + rt * 16 + l15][lg * 8];
#pragma unroll
        for (int ct = 0; ct < 4; ++ct) bfr[ct] = *(const bf16x8*)&Bs[wc * 64 + ct * 16 + l15][lg * 8];
#pragma unroll
        for (int rt = 0; rt < 4; ++rt)
#pragma unroll
            for (int ct = 0; ct < 4; ++ct) acc[rt][ct] = MFMA16(af[rt], bfr[ct], acc[rt][ct]);
    }
#pragma unroll
    for (int rt = 0; rt < 4; ++rt)
#pragma unroll
        for (int ct = 0; ct < 4; ++ct) {
            int n = n0 + wc * 64 + ct * 16 + l15;
            int sec = n >> 9, nn = n & 511, h = nn >> 6, d = nn & 63;
            u16* dst = (sec == 0) ? Q : ((sec == 1) ? K : V);
#pragma unroll
            for (int r = 0; r < 4; ++r) {
                int m = m0 + wr * 64 + rt * 16 + lg * 4 + r;
                int b = m >> 10, pos = m & 1023, bh = b * 8 + h;
                dst[(size_t)bh * 65536 + (size_t)pos * 64 + d] = f2b(acc[rt][ct][r]);
            }
        }
}

// ---------------- V transpose: Vt[bh][d][pos] = V[bh][pos][d] ----------------
__global__ __launch_bounds__(256) void k_transpose_v(const u16* __restrict__ V, u16* __restrict__ Vt) {
    __shared__ u16 tile[64][72];
    const int bh = blockIdx.x >> 4, pt = blockIdx.x & 15;
    const int p0 = pt * 64;
    const int t = threadIdx.x, r = t >> 2, c0 = (t & 3) * 16;
    const bf16x8* src = (const bf16x8*)(V + (size_t)bh * 65536 + (size_t)(p0 + r) * 64 + c0);
    *(bf16x8*)&tile[r][c0] = src[0];
    *(bf16x8*)&tile[r][c0 + 8] = src[1];
    __syncthreads();
    union { u16 u[8]; bf16x8 v; } o0, o1;
#pragma unroll
    for (int ii = 0; ii < 8; ++ii) {
        o0.u[ii] = tile[c0 + ii][r];
        o1.u[ii] = tile[c0 + 8 + ii][r];
    }
    bf16x8* dst = (bf16x8*)(Vt + (size_t)bh * 65536 + (size_t)r * 1024 + p0 + c0);
    dst[0] = o0.v;
    dst[1] = o1.v;
}

// ---------------- flash attention, swapped-operand (S^T) layout ----------------
// R7 with inline-asm v_cvt_pk_bf16_f32 REMOVED (the bisected NaN culprit:
// present in NaN rounds R4/R5/R7, absent in passing R6). packbf (pure C++)
// everywhere. Kept from R7: sdw stride 43 (odd -> conflict-free gather),
// wave-local lgkmcnt fence for the same-wave sdw RAW (2 block barriers/iter).
__global__ __launch_bounds__(512, 2) void k_attn(const u16* __restrict__ Q, const u16* __restrict__ K,
                                                 const u16* __restrict__ Vt, const u16* __restrict__ relb,
                                                 u16* __restrict__ Ob) {
    __shared__ u16 Ks[64][72];       // [j within tile][d]
    __shared__ u16 Vs[64][72];       // [d][j within tile]
    __shared__ u32 sdw[8][16][43];   // per-wave rel band: 80 bf16 in 40 u32, stride 43
    const int t = threadIdx.x, l = t & 63, w = t >> 6;
    const int l15 = l & 15, lg = l >> 4;
    const int g = (blockIdx.x & 7) * 64 + (blockIdx.x >> 3);   // XCD swizzle
    const int bh = g >> 3;
    const int iw = (g & 7) * 128 + w * 16;
    const size_t hb = (size_t)bh * 65536;
    const int srow = t >> 3, scol = (t & 7) * 8;

    bf16x8 qf[2];
#pragma unroll
    for (int kf = 0; kf < 2; ++kf)
        qf[kf] = *(const bf16x8*)(Q + hb + (size_t)(iw + l15) * 64 + kf * 32 + lg * 8);

    f32x4 acc_o[4];
#pragma unroll
    for (int i = 0; i < 4; ++i) acc_o[i] = (f32x4){0.f, 0.f, 0.f, 0.f};
    float m_r = -1e30f, l_r = 0.f;

    // prologue: stage tile 0, prefetch tile 1 into regs
    bf16x8 kreg = *(const bf16x8*)(K + hb + (size_t)srow * 64 + scol);
    bf16x8 vreg = *(const bf16x8*)(Vt + hb + (size_t)srow * 1024 + scol);
    *(bf16x8*)&Ks[srow][scol] = kreg;
    *(bf16x8*)&Vs[srow][scol] = vreg;
    kreg = *(const bf16x8*)(K + hb + (size_t)(64 + srow) * 64 + scol);
    vreg = *(const bf16x8*)(Vt + hb + (size_t)srow * 1024 + 64 + scol);
    __syncthreads();

    for (int j0 = 0; j0 < 1024; j0 += 64) {
        // S^T = mfma(K, Q): acc_s[c][r] = S[q = iw+l15][j = j0 + c*16 + lg*4 + r]
        f32x4 acc_s[4];
#pragma unroll
        for (int c = 0; c < 4; ++c) {
            acc_s[c] = (f32x4){0.f, 0.f, 0.f, 0.f};
#pragma unroll
            for (int kf = 0; kf < 2; ++kf) {
                bf16x8 kb = *(const bf16x8*)&Ks[c * 16 + l15][kf * 32 + lg * 8];
                acc_s[c] = MFMA16(kb, qf[kf], acc_s[c]);
            }
        }
        // band^T = mfma(rel, Q): lane(l15,lg) reg r holds band[t = pt*16+lg*4+r][q-row l15]
        const int bd = iw - j0 - 63;
#pragma unroll
        for (int pt = 0; pt < 5; ++pt) {
            int dd = bd + pt * 16 + l15;
            dd = dd < -512 ? -512 : (dd > 512 ? 512 : dd);
            const u16* rrow = relb + (size_t)(dd + 512) * 64;
            f32x4 a = (f32x4){0.f, 0.f, 0.f, 0.f};
#pragma unroll
            for (int kf = 0; kf < 2; ++kf) {
                bf16x8 rb = *(const bf16x8*)(rrow + kf * 32 + lg * 8);
                a = MFMA16(rb, qf[kf], a);
            }
            int wc32 = pt * 8 + lg * 2;
            sdw[w][l15][wc32] = packbf(a[0], a[1]);
            sdw[w][l15][wc32 + 1] = packbf(a[2], a[3]);
        }
        // wave-local fence for the same-wave sdw RAW (no block barrier needed)
        asm volatile("s_waitcnt lgkmcnt(0)" ::: "memory");
        __builtin_amdgcn_sched_barrier(0);
        // gather band + scale: row is lane-local (l15)
        float sv[4][4];
#pragma unroll
        for (int c = 0; c < 4; ++c)
#pragma unroll
            for (int r = 0; r < 4; ++r) {
                int tt = l15 + 63 - c * 16 - lg * 4 - r;
                u32 wv = sdw[w][l15][tt >> 1];
                float band = b2f((u16)(wv >> ((tt & 1) * 16)));
                sv[c][r] = (acc_s[c][r] + band) * 0.125f;
            }
        // online softmax: in-lane tree + 2 shuffles across the 4 lane-groups
        float mt = sv[0][0];
#pragma unroll
        for (int c = 0; c < 4; ++c)
#pragma unroll
            for (int r = 0; r < 4; ++r) mt = fmaxf(mt, sv[c][r]);
        mt = fmaxf(mt, __shfl_xor(mt, 16, 64));
        mt = fmaxf(mt, __shfl_xor(mt, 32, 64));
        float mnew = fmaxf(m_r, mt);
        float alpha = __expf(m_r - mnew);
        m_r = mnew;
        float p[4][4];
        float rs = 0.f;
#pragma unroll
        for (int c = 0; c < 4; ++c)
#pragma unroll
            for (int r = 0; r < 4; ++r) {
                p[c][r] = __expf(sv[c][r] - mnew);
                rs += p[c][r];
            }
        rs += __shfl_xor(rs, 16, 64);
        rs += __shfl_xor(rs, 32, 64);
        l_r = l_r * alpha + rs;
#pragma unroll
        for (int dt = 0; dt < 4; ++dt)
#pragma unroll
            for (int r = 0; r < 4; ++r) acc_o[dt][r] *= alpha;
        // P B-frags via sigma(kf,lg,e) = kf*32 + (e>>2)*16 + lg*4 + (e&3): lane-local
        union { u32 wd[4]; bf16x8 v; } pb[2];
#pragma unroll
        for (int kf = 0; kf < 2; ++kf)
#pragma unroll
            for (int h = 0; h < 4; ++h) {
                int c = kf * 2 + (h >> 1), r0 = (h & 1) * 2;
                pb[kf].wd[h] = packbf(p[c][r0], p[c][r0 + 1]);
            }
        // O^T += mfma(V, P): acc_o[dt][r] = O[q = iw+l15][dcol = dt*16 + lg*4 + r]
#pragma unroll
        for (int dt = 0; dt < 4; ++dt)
#pragma unroll
            for (int kf = 0; kf < 2; ++kf) {
                union { bf16x4 h[2]; bf16x8 v; } vb;
                vb.h[0] = *(const bf16x4*)&Vs[dt * 16 + l15][kf * 32 + lg * 4];
                vb.h[1] = *(const bf16x4*)&Vs[dt * 16 + l15][kf * 32 + 16 + lg * 4];
                acc_o[dt] = MFMA16(vb.v, pb[kf].v, acc_o[dt]);
            }
        __syncthreads();   // all waves done reading Ks/Vs
        if (j0 + 64 < 1024) {
            *(bf16x8*)&Ks[srow][scol] = kreg;   // implicit vmcnt wait on prefetch
            *(bf16x8*)&Vs[srow][scol] = vreg;
            int jp = j0 / 64 + 2;
            if (jp > 15) jp = 15;
            kreg = *(const bf16x8*)(K + hb + (size_t)(jp * 64 + srow) * 64 + scol);
            vreg = *(const bf16x8*)(Vt + hb + (size_t)srow * 1024 + jp * 64 + scol);
            __syncthreads();   // staged tile visible
        }
    }
    const int b = bh >> 3, h = bh & 7;
    const float rinv = 1.0f / l_r;
    const size_t rowbase = (size_t)(b * 1024 + iw + l15) * 512 + h * 64;
#pragma unroll
    for (int dt = 0; dt < 4; ++dt)
#pragma unroll
        for (int hp = 0; hp < 2; ++hp) {
            u32 pkd = packbf(acc_o[dt][hp * 2] * rinv, acc_o[dt][hp * 2 + 1] * rinv);
            *(u32*)(Ob + rowbase + dt * 16 + lg * 4 + hp * 2) = pkd;
        }
}

// ---------------- GEMM 2: out = Ob @ Wo + bo  (M=8192, N=512, K=512, fp32 out) ----------------
__global__ __launch_bounds__(256) void k_gemm_out(const u16* __restrict__ A, const u16* __restrict__ Bt,
                                                  const float* __restrict__ bias, float* __restrict__ out) {
    __shared__ u16 As[128][40];
    __shared__ u16 Bs[128][40];
    const int t = threadIdx.x, l = t & 63, w = t >> 6;
    const int wr = w >> 1, wc = w & 1, l15 = l & 15, lg = l >> 4;
    const int m0 = blockIdx.x * 128, n0 = blockIdx.y * 128;
    f32x4 acc[4][4];
#pragma unroll
    for (int i = 0; i < 4; ++i)
#pragma unroll
        for (int j = 0; j < 4; ++j) acc[i][j] = (f32x4){0.f, 0.f, 0.f, 0.f};
    const int sr = t >> 1, sko = (t & 1) * 16;
    for (int k0 = 0; k0 < 512; k0 += 32) {
        __syncthreads();
        {
            const bf16x8* pa = (const bf16x8*)(A + (size_t)(m0 + sr) * 512 + k0 + sko);
            *(bf16x8*)&As[sr][sko] = pa[0];
            *(bf16x8*)&As[sr][sko + 8] = pa[1];
            const bf16x8* pb = (const bf16x8*)(Bt + (size_t)(n0 + sr) * 512 + k0 + sko);
            *(bf16x8*)&Bs[sr][sko] = pb[0];
            *(bf16x8*)&Bs[sr][sko + 8] = pb[1];
        }
        __syncthreads();
        bf16x8 af[4], bfr[4];
#pragma unroll
        for (int rt = 0; rt < 4; ++rt) af[rt] = *(const bf16x8*)&As[wr * 64 + rt * 16 + l15][lg * 8];
#pragma unroll
        for (int ct = 0; ct < 4; ++ct) bfr[ct] = *(const bf16x8*)&Bs[wc * 64 + ct * 16 + l15][lg * 8];
#pragma unroll
        for (int rt = 0; rt < 4; ++rt)
#pragma unroll
            for (int ct = 0; ct < 4; ++ct) acc[rt][ct] = MFMA16(af[rt], bfr[ct], acc[rt][ct]);
    }
#pragma unroll
    for (int rt = 0; rt < 4; ++rt)
#pragma unroll
        for (int ct = 0; ct < 4; ++ct) {
            int n = n0 + wc * 64 + ct * 16 + l15;
            float bv = bias[n];
#pragma unroll
            for (int r = 0; r < 4; ++r) {
                int m = m0 + wr * 64 + rt * 16 + lg * 4 + r;
                out[(size_t)m * 512 + n] = acc[rt][ct][r] + bv;
            }
        }
}

extern "C" void kernel_launch(void* const* d_in, const int* in_sizes, int n_in,
                              void* d_out, int out_size, void* d_ws, size_t ws_size,
                              hipStream_t stream) {
    const float* x    = (const float*)d_in[0];
    const float* Wq   = (const float*)d_in[1];
    const float* Wkv  = (const float*)d_in[2];
    const float* rel  = (const float*)d_in[3];
    const float* Wo   = (const float*)d_in[4];
    const float* bo   = (const float*)d_in[5];
    float* out = (float*)d_out;
    char* ws = (char*)d_ws;

    u16* xb   = (u16*)(ws + 0);          //  8,388,608 B
    u16* wqkv = (u16*)(ws + 8388608);    //  1,572,864 B
    u16* wot  = (u16*)(ws + 9961472);    //    524,288 B
    u16* relb = (u16*)(ws + 10485760);   //    131,200 B
    u16* Q    = (u16*)(ws + 10616960);   //  8,388,608 B
    u16* K    = (u16*)(ws + 19005568);   //  8,388,608 B
    u16* V    = (u16*)(ws + 27394176);   //  8,388,608 B
    u16* Vt   = (u16*)(ws + 35782784);   //  8,388,608 B
    u16* Ob   = (u16*)(ws + 44171392);   //  8,388,608 B

    k_f32_to_bf16<<<4096, 256, 0, stream>>>(x, xb, 4194304);
    k_f32_to_bf16<<<65, 256, 0, stream>>>(rel, relb, 65600);
    k_make_wqkv_t<<<3072, 256, 0, stream>>>(Wq, Wkv, wqkv);
    k_make_wo_t<<<1024, 256, 0, stream>>>(Wo, wot);
    k_gemm_qkv<<<dim3(64, 12), 256, 0, stream>>>(xb, wqkv, Q, K, V);
    k_transpose_v<<<1024, 256, 0, stream>>>(V, Vt);
    k_attn<<<512, 512, 0, stream>>>(Q, K, Vt, relb, Ob);
    k_gemm_out<<<dim3(64, 4), 256, 0, stream>>>(Ob, wot, bo, out);
}